// Round 3
// baseline (261.393 us; speedup 1.0000x reference)
//
#include <hip/hip_runtime.h>
#include <hip/hip_bf16.h>

typedef __bf16 bf16x8 __attribute__((ext_vector_type(8)));
typedef float  f32x4  __attribute__((ext_vector_type(4)));
typedef float  f32x16 __attribute__((ext_vector_type(16)));

#define B_  512
#define DX_ 128
#define H_  512

// ---------------------------------------------------------------------------
// prep: one kernel, two jobs.
//  blocks 0..127   : pack W2 -> 32x32x16 B-frag layout PW2[ks2][nt32][lane][8]
//                    (col = nt32*32 + lane&31, k = ks2*16 + (lane>>5)*8 + j)
//  blocks 128..191 : hx = x@W1x ; hyb = y@W1y + b1 from RAW fp32 (16x16 MFMA,
//                    frag gathers from L2) -- the verified round-2 hxy path.
// ---------------------------------------------------------------------------
__global__ __launch_bounds__(256) void prep_kernel(
    const float* __restrict__ x, const float* __restrict__ y,
    const float* __restrict__ W1, const float* __restrict__ W2,
    const float* __restrict__ b1,
    __bf16* __restrict__ PW2, float* __restrict__ hx, float* __restrict__ hyb)
{
    int blk = blockIdx.x;
    int tid = threadIdx.x;
    if (blk < 128) {
        int u   = blk * 256 + tid;            // 0..32767
        int ks2 = u >> 10;                    // 0..31  (K=16 steps)
        int rem = u & 1023;
        int nt  = rem >> 6;                   // 0..15  (32-col tiles)
        int l   = rem & 63;
        int k   = ks2 * 16 + ((l >> 5) << 3);
        int col = nt * 32 + (l & 31);
        const float* p = W2 + k * H_ + col;
        bf16x8 v;
        #pragma unroll
        for (int j = 0; j < 8; ++j) v[j] = (__bf16)p[j * H_];
        *(bf16x8*)(PW2 + u * 8) = v;
        return;
    }
    int b    = blk - 128;
    int task = b >> 5;
    int rem  = b & 31;
    int bm   = rem >> 2, bn = rem & 3;
    const float* A  = task ? y : x;
    const float* Wp = W1 + task * DX_ * H_;
    float* outp = task ? hyb : hx;
    int w = tid >> 6, lane = tid & 63;

    f32x4 acc[4][2] = {};
    #pragma unroll
    for (int ks = 0; ks < 4; ++ks) {
        int k0 = ks * 32 + ((lane >> 4) << 3);
        bf16x8 af[4];
        #pragma unroll
        for (int mt = 0; mt < 4; ++mt) {
            int row = bm * 64 + mt * 16 + (lane & 15);
            const float* pa = A + row * DX_ + k0;
            f32x4 q0 = *(const f32x4*)pa;
            f32x4 q1 = *(const f32x4*)(pa + 4);
            #pragma unroll
            for (int j = 0; j < 4; ++j) {
                af[mt][j]     = (__bf16)q0[j];
                af[mt][j + 4] = (__bf16)q1[j];
            }
        }
        #pragma unroll
        for (int nt = 0; nt < 2; ++nt) {
            int col = bn * 128 + (w * 2 + nt) * 16 + (lane & 15);
            const float* pb = Wp + k0 * H_ + col;
            bf16x8 bv;
            #pragma unroll
            for (int j = 0; j < 8; ++j) bv[j] = (__bf16)pb[j * H_];
            #pragma unroll
            for (int mt = 0; mt < 4; ++mt)
                acc[mt][nt] = __builtin_amdgcn_mfma_f32_16x16x32_bf16(af[mt], bv, acc[mt][nt], 0, 0, 0);
        }
    }
    #pragma unroll
    for (int nt = 0; nt < 2; ++nt) {
        int col = bn * 128 + (w * 2 + nt) * 16 + (lane & 15);
        float badd = task ? b1[col] : 0.f;
        #pragma unroll
        for (int mt = 0; mt < 4; ++mt) {
            #pragma unroll
            for (int r = 0; r < 4; ++r) {
                int row = bm * 64 + mt * 16 + ((lane >> 4) << 2) + r;
                outp[row * H_ + col] = acc[mt][nt][r] + badd;
            }
        }
    }
}

// ---------------------------------------------------------------------------
// critic: per block 128 pair-rows (16 i x 8 j) x all 512 cols.
// 32x32x16 MFMA; h1 generated on the fly into a 3-deep ring of swizzled LDS
// chunks (1 barrier per 32-K step); wave-phase stagger (mw=0: MFMA then gen,
// mw=1: gen then MFMA) so matrix and VALU pipes overlap across SIMD-paired
// waves. Epilogue fuses b2/relu/W3/b3 + 32-lane butterfly row-reduce.
// ---------------------------------------------------------------------------
__global__ __launch_bounds__(512, 2) void critic_kernel(
    const float* __restrict__ hx, const float* __restrict__ hyb,
    const __bf16* __restrict__ PW2,
    const float* __restrict__ b2, const float* __restrict__ W3,
    const float* __restrict__ b3, float* __restrict__ out)
{
    __shared__ float hx_s[16 * 516];
    __shared__ float hy_s[8 * 516];
    __shared__ __align__(16) char h1_s[3 * 8192];   // ring of [128 rows][32 k] bf16
    __shared__ float sc_s[128];

    int tid = threadIdx.x;
    int lane = tid & 63, wid = tid >> 6;
    int mw = wid >> 2, nw = wid & 3;
    int bj = blockIdx.x, bi = blockIdx.y;

    // ---- prologue: stage hx/hyb rows; init sc_s
    for (int idx = tid; idx < 16 * 128; idx += 512) {
        int r = idx >> 7, c4 = (idx & 127) << 2;
        *(f32x4*)&hx_s[r * 516 + c4] = *(const f32x4*)&hx[(bi * 16 + r) * H_ + c4];
    }
    for (int idx = tid; idx < 8 * 128; idx += 512) {
        int r = idx >> 7, c4 = (idx & 127) << 2;
        *(f32x4*)&hy_s[r * 516 + c4] = *(const f32x4*)&hyb[(bj * 8 + r) * H_ + c4];
    }
    if (tid < 128) sc_s[tid] = 0.f;

    // gen mapping: thread -> (pair-row grow = tid>>2, k-octet q = tid&3)
    int grow = tid >> 2, q = tid & 3;
    const float* px = &hx_s[(grow >> 3) * 516 + q * 8];
    const float* py = &hy_s[(grow & 7) * 516 + q * 8];
    const int woff = grow * 64 + ((q ^ ((grow >> 1) & 3)) << 4);  // conflict-free swizzle

    // A-fragment read offsets [t][mt]: row = mw*64+mt*32+(l&31), octet = t*2+(l>>5)
    int aoff[2][2];
    #pragma unroll
    for (int t = 0; t < 2; ++t)
        #pragma unroll
        for (int mt = 0; mt < 2; ++mt) {
            int row  = mw * 64 + mt * 32 + (lane & 31);
            int slot = (t * 2 + (lane >> 5)) ^ ((row >> 1) & 3);
            aoff[t][mt] = row * 64 + (slot << 4);
        }

    f32x16 acc[2][4] = {};

    auto GEN = [&](int g) {
        const f32x4 a0 = *(const f32x4*)(px + g * 32);
        const f32x4 a1 = *(const f32x4*)(px + g * 32 + 4);
        const f32x4 c0 = *(const f32x4*)(py + g * 32);
        const f32x4 c1 = *(const f32x4*)(py + g * 32 + 4);
        f32x4 s0 = a0 + c0, s1 = a1 + c1;
        bf16x8 hv;
        #pragma unroll
        for (int j = 0; j < 4; ++j) {
            hv[j]     = (__bf16)fmaxf(s0[j], 0.f);
            hv[j + 4] = (__bf16)fmaxf(s1[j], 0.f);
        }
        *(bf16x8*)(h1_s + (g % 3) * 8192 + woff) = hv;
    };

    auto STEP = [&](int ks) {
        const char* base = h1_s + (ks % 3) * 8192;
        bf16x8 a00 = *(const bf16x8*)(base + aoff[0][0]);
        bf16x8 a01 = *(const bf16x8*)(base + aoff[0][1]);
        bf16x8 a10 = *(const bf16x8*)(base + aoff[1][0]);
        bf16x8 a11 = *(const bf16x8*)(base + aoff[1][1]);
        const __bf16* pb = PW2 + ((ks * 2) * 16 + nw * 4) * 512 + lane * 8;
        #pragma unroll
        for (int t = 0; t < 2; ++t) {
            #pragma unroll
            for (int nt = 0; nt < 4; ++nt) {
                bf16x8 bv = *(const bf16x8*)(pb + t * 8192 + nt * 512);
                acc[0][nt] = __builtin_amdgcn_mfma_f32_32x32x16_bf16(t ? a10 : a00, bv, acc[0][nt], 0, 0, 0);
                acc[1][nt] = __builtin_amdgcn_mfma_f32_32x32x16_bf16(t ? a11 : a01, bv, acc[1][nt], 0, 0, 0);
            }
        }
    };

    __syncthreads();            // hx_s/hy_s staged
    GEN(0);
    GEN(1);
    __syncthreads();            // buf0, buf1 ready

    #pragma unroll
    for (int ks = 0; ks < 16; ++ks) {
        if (mw == 0) {
            STEP(ks);
            if (ks < 14) GEN(ks + 2);
        } else {
            if (ks < 14) GEN(ks + 2);
            STEP(ks);
        }
        if (ks < 15) __syncthreads();
    }

    // ---- epilogue: score[row] = b3 + sum_col relu(acc + b2[col]) * W3[col]
    float b2v[4], w3v[4];
    #pragma unroll
    for (int nt = 0; nt < 4; ++nt) {
        int col = nw * 128 + nt * 32 + (lane & 31);
        b2v[nt] = b2[col];
        w3v[nt] = W3[col];
    }
    #pragma unroll
    for (int mt = 0; mt < 2; ++mt) {
        #pragma unroll
        for (int r = 0; r < 16; ++r) {
            float s = 0.f;
            #pragma unroll
            for (int nt = 0; nt < 4; ++nt) {
                float h2 = fmaxf(acc[mt][nt][r] + b2v[nt], 0.f);
                s += h2 * w3v[nt];
            }
            s += __shfl_xor(s, 1);
            s += __shfl_xor(s, 2);
            s += __shfl_xor(s, 4);
            s += __shfl_xor(s, 8);
            s += __shfl_xor(s, 16);
            if ((lane & 31) == 0) {
                int prow = mw * 64 + mt * 32 + ((r & 3) + 8 * (r >> 2)) + ((lane >> 5) << 2);
                atomicAdd(&sc_s[prow], s);
            }
        }
    }
    __syncthreads();
    if (tid < 128) {
        int i = bi * 16 + (tid >> 3);
        int j = bj * 8 + (tid & 7);
        out[i * B_ + j] = sc_s[tid] + b3[0];
    }
}

// ---------------------------------------------------------------------------
extern "C" void kernel_launch(void* const* d_in, const int* in_sizes, int n_in,
                              void* d_out, int out_size, void* d_ws, size_t ws_size,
                              hipStream_t stream)
{
    const float* x  = (const float*)d_in[0];
    const float* y  = (const float*)d_in[1];
    const float* W1 = (const float*)d_in[2];
    const float* b1 = (const float*)d_in[3];
    const float* W2 = (const float*)d_in[4];
    const float* b2 = (const float*)d_in[5];
    const float* W3 = (const float*)d_in[6];
    const float* b3 = (const float*)d_in[7];
    float* out = (float*)d_out;

    char* ws = (char*)d_ws;
    float*  hx  = (float*)(ws);                    // 1 MB
    float*  hyb = (float*)(ws + 1048576);          // 1 MB
    __bf16* PW2 = (__bf16*)(ws + 2097152);         // 512 KB (end: 2.5 MB)

    hipLaunchKernelGGL(prep_kernel, dim3(192), dim3(256), 0, stream,
                       x, y, W1, W2, b1, PW2, hx, hyb);
    hipLaunchKernelGGL(critic_kernel, dim3(64, 32), dim3(512), 0, stream,
                       hx, hyb, PW2, b2, W3, b3, out);
}